// Round 14
// baseline (918.492 us; speedup 1.0000x reference)
//
#include <hip/hip_runtime.h>
#include <math.h>

#define B 16
#define CH 128
#define DIM 128
#define MODES 32
#define NLAYERS 4
#define PROJ 128
#define U 64            // stored kx modes: u<32 -> kx=u ; u>=32 -> kx=u+64 (96..127)
#define KY 32
#define NMODE (U*KY)    // 2048
#define N2 (DIM*DIM)    // 16384
#define PG 32           // p-groups in idft
#define PPG (PROJ/PG)   // 4 p per group

__device__ __forceinline__ void async16(const void* g, void* l) {
  __builtin_amdgcn_global_load_lds((const __attribute__((address_space(1))) unsigned int*)g,
                                   (__attribute__((address_space(3))) unsigned int*)l, 16, 0, 0);
}

// ---------------- K1a: t1[b][x][ky] = sum_y z[b][x][y] e^{-2pi i ky y/128} ----------------
__global__ __launch_bounds__(256) void k_zf1(const float* __restrict__ z,
                                             float2* __restrict__ t1) {
  __shared__ float zrow[16][DIM];
  __shared__ float2 tw[DIM];
  int bid = blockIdx.x;
  int b = bid >> 3, xt = bid & 7;
  int x0 = xt * 16;
  int t = threadIdx.x;
  if (t < 128) {
    float ang = (float)(2.0 * M_PI) * (float)t / 128.0f;
    tw[t] = make_float2(cosf(ang), sinf(ang));
  }
  for (int e = t; e < 16 * DIM / 4; e += 256)
    ((float4*)&zrow[0][0])[e] = ((const float4*)&z[b * N2 + x0 * DIM])[e];
  __syncthreads();
  #pragma unroll
  for (int j = 0; j < 2; ++j) {
    int it = t + j * 256;
    int x_l = it >> 5, ky = it & 31;
    float tr = 0.f, ti = 0.f;
    for (int y = 0; y < DIM; ++y) {
      float v = zrow[x_l][y];
      float2 w = tw[(ky * y) & 127];
      tr += v * w.x;
      ti -= v * w.y;
    }
    t1[((size_t)b * DIM + x0 + x_l) * KY + ky] = make_float2(tr, ti);
  }
}

// ---------------- K1b: zf[b][u][ky] = sum_x t1[b][x][ky] e^{-2pi i kx x/128} ----------------
__global__ __launch_bounds__(256) void k_zf2(const float2* __restrict__ t1,
                                             float* __restrict__ zfr, float* __restrict__ zfi) {
  __shared__ float2 t1s[DIM][KY];
  __shared__ float2 tw[DIM];
  int bid = blockIdx.x;
  int b = bid >> 1, uh = bid & 1;
  int t = threadIdx.x;
  if (t < 128) {
    float ang = (float)(2.0 * M_PI) * (float)t / 128.0f;
    tw[t] = make_float2(cosf(ang), sinf(ang));
  }
  for (int e = t; e < DIM * KY / 2; e += 256)
    ((float4*)&t1s[0][0])[e] = ((const float4*)&t1[(size_t)b * DIM * KY])[e];
  __syncthreads();
  #pragma unroll
  for (int j = 0; j < 4; ++j) {
    int m = t + j * 256;
    int u_l = m >> 5, ky = m & 31;
    int u = uh * 32 + u_l;
    int kx = (u < 32) ? u : (u + 64);
    float ar = 0.f, ai = 0.f;
    for (int x = 0; x < DIM; ++x) {
      float2 v = t1s[x][ky];
      float2 w = tw[(kx * x) & 127];
      ar += v.x * w.x + v.y * w.y;
      ai += v.y * w.x - v.x * w.y;
    }
    zfr[b * NMODE + u * KY + ky] = ar;
    zfi[b * NMODE + u * KY + ky] = ai;
  }
}

// ---------------- K2: lift in spectral space (float2 out) ----------------
__global__ __launch_bounds__(256) void k_lift(const float* __restrict__ zfr, const float* __restrict__ zfi,
                                              const float* __restrict__ lw, const float* __restrict__ lb,
                                              float2* __restrict__ vcout) {
  int idx = blockIdx.x * 256 + threadIdx.x;
  if (idx >= B * CH * NMODE) return;
  int m = idx & (NMODE - 1);
  int c = (idx >> 11) & 127;
  int b = idx >> 18;
  float w = lw[c];
  float re = w * zfr[b * NMODE + m];
  float im = w * zfi[b * NMODE + m];
  if (m == 0) re += 16384.f * lb[c];
  vcout[idx] = make_float2(re, im);
}

// ---------------- K3: spectral einsum, one layer ----------------
// Empirical law (r8/r11/r12/r13): per-block async16 stream ~6.5 GB/s regardless of
// schedule/chunk size; aggregate = resident blocks x rate. So: MAXIMIZE resident blocks.
// grid = 2048 = 64u x 16ot(o-tile 8) x 2bh(b-half 8); 16 KB LDS dbuf -> 8 blocks/CU
// (wave cap). Per block: W 256 KB + V 256 KB. Same-u blocks pinned to one XCD (V + W
// twin reads are L2 hits; W HBM fetch stays ~1x). Thread owns 4o x 2b (16-float acc).
__global__ __launch_bounds__(256) void k_spec(const float2* __restrict__ vc,
                                              const float* __restrict__ wr1, const float* __restrict__ wi1,
                                              const float* __restrict__ wr2, const float* __restrict__ wi2,
                                              float2* __restrict__ oc) {
  __shared__ float  lW[2][4][8][32];        // [buf][ri*2+il][o_l][ky]  8 KB
  __shared__ float2 lV[2][2][8][32];        // [buf][il][b_l][ky]       8 KB
  int bid = blockIdx.x;
  int u = ((bid & 7) << 3) | ((bid >> 3) & 7);
  int rest = bid >> 6;                      // 0..31
  int o0 = (rest & 15) * 8;
  int b0 = (rest >> 4) * 8;
  int kxw = u & 31;
  const float* wr = (u >= 32) ? wr2 : wr1;
  const float* wi = (u >= 32) ? wi2 : wi1;
  int t = threadIdx.x;
  int ky = t & 31, q = t >> 5;              // q: 3 bits
  int oh = q >> 2, bq = q & 3;              // thread: o = o0+oh*4+j, b = b0+bq*2+bb
  int wv = t >> 6, lane = t & 63;
  float accR[4][2] = {}, accI[4][2] = {};

  // chunk = 2 i's = 8 KB: units 0..3 = W (ri*2+il), units 4..7 = V (il*2+half).
  // Each wave issues exactly 2 async16 per chunk.
  #define STAGE(bf, i0)                                                              \
    {                                                                                \
      _Pragma("unroll")                                                              \
      for (int n = 0; n < 2; ++n) {                                                  \
        int nu = wv * 2 + n;                                                         \
        if (nu < 4) {                                                                \
          int ri = nu >> 1, il = nu & 1;                                             \
          int o_l = lane >> 3, ky4 = (lane & 7) * 4;                                 \
          const float* src = (ri ? wi : wr) +                                        \
            (((size_t)((i0) + il) * CH + o0 + o_l) * MODES + kxw) * MODES + ky4;     \
          async16(src, (char*)&lW[bf][0][0][0] + (size_t)nu * 1024 + lane * 16);     \
        } else {                                                                     \
          int nv = nu - 4;                                                           \
          int il = nv >> 1, h = nv & 1;                                              \
          int b_l = h * 4 + (lane >> 4), ky2 = (lane & 15) * 2;                      \
          const float2* src = vc + ((size_t)(b0 + b_l) * CH + (i0) + il) * NMODE +   \
                              u * KY + ky2;                                          \
          async16(src, (char*)&lV[bf][0][0][0] + (size_t)nv * 1024 + lane * 16);     \
        }                                                                            \
      }                                                                              \
    }

  #define COMPUTE(bf)                                                                \
    {                                                                                \
      _Pragma("unroll")                                                              \
      for (int il = 0; il < 2; ++il) {                                               \
        float wrv[4], wiv[4];                                                        \
        _Pragma("unroll")                                                            \
        for (int j = 0; j < 4; ++j) {                                                \
          wrv[j] = lW[bf][il][oh * 4 + j][ky];                                       \
          wiv[j] = lW[bf][2 + il][oh * 4 + j][ky];                                   \
        }                                                                            \
        _Pragma("unroll")                                                            \
        for (int bb = 0; bb < 2; ++bb) {                                             \
          float2 v = lV[bf][il][bq * 2 + bb][ky];                                    \
          _Pragma("unroll")                                                          \
          for (int j = 0; j < 4; ++j) {                                              \
            accR[j][bb] += wrv[j] * v.x - wiv[j] * v.y;                              \
            accI[j][bb] += wrv[j] * v.y + wiv[j] * v.x;                              \
          }                                                                          \
        }                                                                            \
      }                                                                              \
    }

  STAGE(0, 0);
  for (int k = 0; k < 64; ++k) {
    int cur = k & 1;
    __syncthreads();                        // chunk k staged; prior buf reads done
    if (k + 1 < 64) STAGE(cur ^ 1, (k + 1) * 2);
    COMPUTE(cur);
  }
  #undef STAGE
  #undef COMPUTE
  #pragma unroll
  for (int j = 0; j < 4; ++j)
    #pragma unroll
    for (int bb = 0; bb < 2; ++bb) {
      int o = o0 + oh * 4 + j, b = b0 + bq * 2 + bb;
      oc[(((size_t)b * CH + o) * U + u) * KY + ky] = make_float2(accR[j][bb], accI[j][bb]);
    }
}

// ---------------- K3b: Hermitian projection of ky=0 column ----------------
__global__ __launch_bounds__(256) void k_proj0(float2* __restrict__ vc) {
  int idx = blockIdx.x * 256 + threadIdx.x;   // B*CH*33
  if (idx >= B * CH * 33) return;
  int pi = idx % 33;
  int bc = idx / 33;
  float2* base = vc + (size_t)bc * NMODE;
  if (pi == 0) {
    base[0].y = 0.f;
  } else if (pi == 32) {
    base[32 * KY].x *= 0.5f;
    base[32 * KY].y *= 0.5f;
  } else {
    int ua = pi, ub = 64 - pi;
    float2 a = base[ua * KY], b2 = base[ub * KY];
    base[ua * KY] = make_float2(0.5f * (a.x + b2.x), 0.5f * (a.y - b2.y));
    base[ub * KY] = make_float2(0.5f * (b2.x + a.x), 0.5f * (b2.y - a.y));
  }
}

// ---------------- K4: pw1 in spectral space (float2 io), XCD-pinned per batch ----------------
__global__ __launch_bounds__(256) void k_pw1(const float2* __restrict__ xc,
                                             const float* __restrict__ pw1,
                                             float2* __restrict__ hc) {
  __shared__ float wT[CH][CH + 1];
  int bid = blockIdx.x;
  int b = ((bid & 7) << 1) | ((bid >> 8) & 1);
  int jt = (bid >> 3) & 31;
  int t = threadIdx.x;
  for (int e = t; e < CH * CH; e += 256) {
    int p = e >> 7, c = e & 127;
    wT[c][p] = pw1[e];
  }
  __syncthreads();
  int tx = t & 15, ty = t >> 4;
  int j0 = jt * 64 + tx * 4;
  float accR[4][8] = {}, accI[4][8] = {};
  for (int c = 0; c < CH; ++c) {
    const float4* x4 = (const float4*)&xc[((size_t)b * CH + c) * NMODE + j0];
    float4 v0 = x4[0], v1 = x4[1];
    float xrv[4] = {v0.x, v0.z, v1.x, v1.z};
    float xiv[4] = {v0.y, v0.w, v1.y, v1.w};
    float w[8];
    #pragma unroll
    for (int pp = 0; pp < 8; ++pp) w[pp] = wT[c][ty * 8 + pp];
    #pragma unroll
    for (int jj = 0; jj < 4; ++jj)
      #pragma unroll
      for (int pp = 0; pp < 8; ++pp) {
        accR[jj][pp] += w[pp] * xrv[jj];
        accI[jj][pp] += w[pp] * xiv[jj];
      }
  }
  #pragma unroll
  for (int pp = 0; pp < 8; ++pp) {
    int p = ty * 8 + pp;
    float4* o4 = (float4*)&hc[((size_t)b * CH + p) * NMODE + j0];
    o4[0] = make_float4(accR[0][pp], accI[0][pp], accR[1][pp], accI[1][pp]);
    o4[1] = make_float4(accR[2][pp], accI[2][pp], accR[3][pp], accI[3][pp]);
  }
}

// ---------------- K5: fused iDFT + bias + gelu + pw2, parity + async dbuf + E-tile ----------------
// grid = 4096: b = (bid&7)|(((bid>>3)&1)<<3) (XCD-pinned b), pg = (bid>>4)&31, xs = bid>>9.
__global__ __launch_bounds__(256) void k_idft_partial(const float2* __restrict__ hc,
                                                      const float* __restrict__ pb1,
                                                      const float* __restrict__ pw2,
                                                      float* __restrict__ partial) {
  __shared__ float2 tw[DIM];                  // 1 KB
  __shared__ float2 hfs[2][NMODE];            // 32 KB dbuf
  __shared__ float2 sbuf[16][KY];             // [x-slot][ky] 4 KB
  __shared__ float4 sE[8][32];                // E-tile 4 KB
  int bid = blockIdx.x;
  int b = (bid & 7) | (((bid >> 3) & 1) << 3);
  int pg = (bid >> 4) & 31, xs = bid >> 9;
  int x0 = xs * 8;
  int t = threadIdx.x;
  int wv = t >> 6, lane = t & 63;
  if (t < 128) {
    float ang = (float)(2.0 * M_PI) * (float)t / 128.0f;
    tw[t] = make_float2(cosf(ang), sinf(ang));
  }

  #define STAGE_H(bf, pp_)                                                           \
    {                                                                                \
      const char* srcb = (const char*)(hc + ((size_t)b * CH + pg * PPG + (pp_)) * NMODE); \
      _Pragma("unroll")                                                              \
      for (int n = 0; n < 4; ++n) {                                                  \
        int nu = wv * 4 + n;                                                         \
        async16(srcb + (size_t)nu * 1024 + lane * 16,                                \
                (char*)&hfs[bf][0] + (size_t)nu * 1024 + lane * 16);                 \
      }                                                                              \
    }

  STAGE_H(0, 0);
  __syncthreads();                            // tw + hfs[0] ready
  {
    int xq = t >> 5, j = t & 31;
    int x = x0 + xq;
    int kxE = (j < 16) ? (2 * j) : (2 * j + 64);
    float2 wE = tw[(kxE * x) & 127];
    float2 wO = tw[((kxE + 1) * x) & 127];
    sE[xq][j] = make_float4(wE.x, wE.y, wO.x, wO.y);
  }
  int y = t & 63, xh = t >> 6;
  float Cr[KY], Sr[KY];
  #pragma unroll
  for (int ky = 0; ky < KY; ++ky) {
    float2 w = tw[(ky * y) & 127];
    float wk = (ky == 0) ? 1.f : 2.f;
    Cr[ky] = wk * w.x;
    Sr[ky] = -wk * w.y;
  }
  __syncthreads();                            // sE visible to all
  int xqA = t >> 5, kyA = t & 31;
  float res[8] = {0.f, 0.f, 0.f, 0.f, 0.f, 0.f, 0.f, 0.f};
  for (int pp = 0; pp < PPG; ++pp) {
    int p = pg * PPG + pp;
    int cur = pp & 1;
    if (pp) __syncthreads();                  // hfs[cur] staged; sbuf free
    if (pp + 1 < PPG) STAGE_H(cur ^ 1, pp + 1);
    // phase A with u-parity via E-tile: s[x]=Pe+Po, s[x+64]=Pe-Po
    {
      float per = 0.f, pei = 0.f, por = 0.f, poi = 0.f;
      #pragma unroll
      for (int j = 0; j < 32; ++j) {
        float4 E = sE[xqA][j];
        float2 h0 = hfs[cur][(2 * j) * KY + kyA];
        float2 h1 = hfs[cur][(2 * j + 1) * KY + kyA];
        per += h0.x * E.x - h0.y * E.y;
        pei += h0.x * E.y + h0.y * E.x;
        por += h1.x * E.z - h1.y * E.w;
        poi += h1.x * E.w + h1.y * E.z;
      }
      sbuf[xqA][kyA]     = make_float2(per + por, pei + poi);
      sbuf[xqA + 8][kyA] = make_float2(per - por, pei - poi);
    }
    __syncthreads();
    // phase B with ky-parity: out[y] = Ae+Ao, out[y+64] = Ae-Ao (float4 sbuf reads)
    float pb = pb1[p], pw = pw2[p];
    #pragma unroll
    for (int sl = 0; sl < 4; ++sl) {
      int s_i = xh + sl * 4;
      float ae = 0.f, ao = 0.f;
      #pragma unroll
      for (int ky = 0; ky < KY; ky += 2) {
        float4 v = *(const float4*)&sbuf[s_i][ky];   // {re_ky, im_ky, re_ky1, im_ky1}
        ae += v.x * Cr[ky] + v.y * Sr[ky];
        ao += v.z * Cr[ky + 1] + v.w * Sr[ky + 1];
      }
      float hlo = (ae + ao) * (1.f / 16384.f) + pb;
      float hhi = (ae - ao) * (1.f / 16384.f) + pb;
      float zlo = 1.5957691216057308f * (hlo + 0.044715f * hlo * hlo * hlo);
      float zhi = 1.5957691216057308f * (hhi + 0.044715f * hhi * hhi * hhi);
      res[sl * 2]     += pw * hlo * __builtin_amdgcn_rcpf(1.f + __expf(-zlo));
      res[sl * 2 + 1] += pw * hhi * __builtin_amdgcn_rcpf(1.f + __expf(-zhi));
    }
  }
  #undef STAGE_H
  size_t pbase = ((size_t)pg * B + b) * N2;
  #pragma unroll
  for (int sl = 0; sl < 4; ++sl) {
    int s_i = xh + sl * 4;
    int x = x0 + (s_i & 7) + ((s_i >> 3) << 6);
    partial[pbase + x * DIM + y]      = res[sl * 2];
    partial[pbase + x * DIM + y + 64] = res[sl * 2 + 1];
  }
}

// ---------------- K6: reduce p-group partials + pb2 ----------------
__global__ __launch_bounds__(256) void k_reduce(const float* __restrict__ partial,
                                                const float* __restrict__ pb2,
                                                float* __restrict__ outp) {
  int idx = blockIdx.x * 256 + threadIdx.x;
  if (idx >= B * N2) return;
  float s = pb2[0];
  #pragma unroll
  for (int pg = 0; pg < PG; ++pg) s += partial[(size_t)pg * B * N2 + idx];
  outp[idx] = s;
}

extern "C" void kernel_launch(void* const* d_in, const int* in_sizes, int n_in,
                              void* d_out, int out_size, void* d_ws, size_t ws_size,
                              hipStream_t stream) {
  const float* z   = (const float*)d_in[0];
  const float* lw  = (const float*)d_in[1];
  const float* lb  = (const float*)d_in[2];
  const float* wr1 = (const float*)d_in[3];
  const float* wi1 = (const float*)d_in[4];
  const float* wr2 = (const float*)d_in[5];
  const float* wi2 = (const float*)d_in[6];
  const float* pw1 = (const float*)d_in[7];
  const float* pb1 = (const float*)d_in[8];
  const float* pw2 = (const float*)d_in[9];
  const float* pb2 = (const float*)d_in[10];
  float* out = (float*)d_out;
  float* ws = (float*)d_ws;

  float* zfr = ws;
  float* zfi = zfr + 32768;
  float2* Ac = (float2*)(ws + 65536);
  float2* Bc = Ac + (size_t)B * CH * NMODE;
  float2* t1 = Bc;   // aliases Bc (dead until first k_spec write)

  k_zf1<<<B * 8, 256, 0, stream>>>(z, t1);
  k_zf2<<<B * 2, 256, 0, stream>>>(t1, zfr, zfi);
  k_lift<<<(B * CH * NMODE) / 256, 256, 0, stream>>>(zfr, zfi, lw, lb, Ac);

  const size_t WSTRIDE = (size_t)CH * CH * MODES * MODES;
  float2 *ir = Ac, *oc = Bc;
  for (int l = 0; l < NLAYERS; ++l) {
    k_spec<<<2048, 256, 0, stream>>>(ir,
                                     wr1 + l * WSTRIDE, wi1 + l * WSTRIDE,
                                     wr2 + l * WSTRIDE, wi2 + l * WSTRIDE,
                                     oc);
    if (l < NLAYERS - 1)
      k_proj0<<<(B * CH * 33 + 255) / 256, 256, 0, stream>>>(oc);
    float2* tmp = ir; ir = oc; oc = tmp;
  }
  k_pw1<<<512, 256, 0, stream>>>(ir, pw1, oc);
  float* partial = (float*)ir;   // aliases Ac (33.5 MB < 67 MB, dead after k_pw1)
  k_idft_partial<<<B * PG * 8, 256, 0, stream>>>(oc, pb1, pw2, partial);
  k_reduce<<<(B * N2) / 256, 256, 0, stream>>>(partial, pb2, out);
}

// Round 15
// 817.103 us; speedup vs baseline: 1.1241x; 1.1241x over previous
//
#include <hip/hip_runtime.h>
#include <math.h>

#define B 16
#define CH 128
#define DIM 128
#define MODES 32
#define NLAYERS 4
#define PROJ 128
#define U 64            // stored kx modes: u<32 -> kx=u ; u>=32 -> kx=u+64 (96..127)
#define KY 32
#define NMODE (U*KY)    // 2048
#define N2 (DIM*DIM)    // 16384
#define PG 32           // p-groups in idft
#define PPG (PROJ/PG)   // 4 p per group

__device__ __forceinline__ void async16(const void* g, void* l) {
  __builtin_amdgcn_global_load_lds((const __attribute__((address_space(1))) unsigned int*)g,
                                   (__attribute__((address_space(3))) unsigned int*)l, 16, 0, 0);
}

// ---------------- K1a: t1[b][x][ky] = sum_y z[b][x][y] e^{-2pi i ky y/128} ----------------
__global__ __launch_bounds__(256) void k_zf1(const float* __restrict__ z,
                                             float2* __restrict__ t1) {
  __shared__ float zrow[16][DIM];
  __shared__ float2 tw[DIM];
  int bid = blockIdx.x;
  int b = bid >> 3, xt = bid & 7;
  int x0 = xt * 16;
  int t = threadIdx.x;
  if (t < 128) {
    float ang = (float)(2.0 * M_PI) * (float)t / 128.0f;
    tw[t] = make_float2(cosf(ang), sinf(ang));
  }
  for (int e = t; e < 16 * DIM / 4; e += 256)
    ((float4*)&zrow[0][0])[e] = ((const float4*)&z[b * N2 + x0 * DIM])[e];
  __syncthreads();
  #pragma unroll
  for (int j = 0; j < 2; ++j) {
    int it = t + j * 256;
    int x_l = it >> 5, ky = it & 31;
    float tr = 0.f, ti = 0.f;
    for (int y = 0; y < DIM; ++y) {
      float v = zrow[x_l][y];
      float2 w = tw[(ky * y) & 127];
      tr += v * w.x;
      ti -= v * w.y;
    }
    t1[((size_t)b * DIM + x0 + x_l) * KY + ky] = make_float2(tr, ti);
  }
}

// ---------------- K1b: zf[b][u][ky] = sum_x t1[b][x][ky] e^{-2pi i kx x/128} ----------------
__global__ __launch_bounds__(256) void k_zf2(const float2* __restrict__ t1,
                                             float* __restrict__ zfr, float* __restrict__ zfi) {
  __shared__ float2 t1s[DIM][KY];
  __shared__ float2 tw[DIM];
  int bid = blockIdx.x;
  int b = bid >> 1, uh = bid & 1;
  int t = threadIdx.x;
  if (t < 128) {
    float ang = (float)(2.0 * M_PI) * (float)t / 128.0f;
    tw[t] = make_float2(cosf(ang), sinf(ang));
  }
  for (int e = t; e < DIM * KY / 2; e += 256)
    ((float4*)&t1s[0][0])[e] = ((const float4*)&t1[(size_t)b * DIM * KY])[e];
  __syncthreads();
  #pragma unroll
  for (int j = 0; j < 4; ++j) {
    int m = t + j * 256;
    int u_l = m >> 5, ky = m & 31;
    int u = uh * 32 + u_l;
    int kx = (u < 32) ? u : (u + 64);
    float ar = 0.f, ai = 0.f;
    for (int x = 0; x < DIM; ++x) {
      float2 v = t1s[x][ky];
      float2 w = tw[(kx * x) & 127];
      ar += v.x * w.x + v.y * w.y;
      ai += v.y * w.x - v.x * w.y;
    }
    zfr[b * NMODE + u * KY + ky] = ar;
    zfi[b * NMODE + u * KY + ky] = ai;
  }
}

// ---------------- K2: lift in spectral space (float2 out) ----------------
__global__ __launch_bounds__(256) void k_lift(const float* __restrict__ zfr, const float* __restrict__ zfi,
                                              const float* __restrict__ lw, const float* __restrict__ lb,
                                              float2* __restrict__ vcout) {
  int idx = blockIdx.x * 256 + threadIdx.x;
  if (idx >= B * CH * NMODE) return;
  int m = idx & (NMODE - 1);
  int c = (idx >> 11) & 127;
  int b = idx >> 18;
  float w = lw[c];
  float re = w * zfr[b * NMODE + m];
  float im = w * zfi[b * NMODE + m];
  if (m == 0) re += 16384.f * lb[c];
  vcout[idx] = make_float2(re, im);
}

// ---------------- K3: spectral einsum, one layer ----------------
// Model (r8..r14): time ~ total staged bytes / ~5 TB/s. Minimize staged bytes:
// block = (u, o-tile 32) x ALL 16 b, 512 threads, grid 256 (1 block/CU).
// Staged/layer: W 268 MB (x1) + V 134 MB (x4) = 402 MB (-25% vs r8's 536).
// chunk = 4 i = 48 KB [W 32 KB | V 16 KB]; ring-3 (144 KB LDS); counted vmcnt:
// every wave (8) issues exactly 6 async16/chunk -> depth-2 = vmcnt(6), never drains
// (essential at 1 block/CU: no sibling block to hide barrier stalls).
__global__ __launch_bounds__(512) void k_spec(const float2* __restrict__ vc,
                                              const float* __restrict__ wr1, const float* __restrict__ wi1,
                                              const float* __restrict__ wr2, const float* __restrict__ wi2,
                                              float2* __restrict__ oc) {
  __shared__ float4 ring[3][3072];          // 3 x 48 KB = 144 KB
  int bid = blockIdx.x;
  int u = ((bid & 7) << 3) | ((bid >> 3) & 7);   // same-u blocks -> same XCD
  int ot = bid >> 6;                        // 0..3
  int o0 = ot * 32;
  int kxw = u & 31;
  const float* wr = (u >= 32) ? wr2 : wr1;
  const float* wi = (u >= 32) ? wi2 : wi1;
  int t = threadIdx.x;                      // 0..511
  int ky = t & 31, oh = (t >> 5) & 7, bh = t >> 8;   // o = o0+oh*4+j, b = bh*8+bb
  int wv = t >> 6, lane = t & 63;           // wv 0..7
  float accR[4][8] = {}, accI[4][8] = {};

  // 48 units of 1 KB per chunk: units 0..31 = W [ri][il][o-oct], 32..47 = V [il][b-quad]
  #define STAGE(c)                                                                   \
    if ((c) < 32) {                                                                  \
      char* dst0 = (char*)&ring[0][0] + (size_t)((c) % 3) * 49152;                   \
      int i0_ = (c) * 4;                                                             \
      _Pragma("unroll")                                                              \
      for (int n = 0; n < 6; ++n) {                                                  \
        int nu = wv * 6 + n;                                                         \
        if (nu < 32) {                                                               \
          int ri = nu >> 4, il = (nu >> 2) & 3, oo = nu & 3;                         \
          int o_l = oo * 8 + (lane >> 3), ky4 = (lane & 7) * 4;                      \
          const float* src = (ri ? wi : wr) +                                        \
            (((size_t)(i0_ + il) * CH + o0 + o_l) * MODES + kxw) * MODES + ky4;      \
          async16(src, dst0 + (size_t)nu * 1024 + lane * 16);                        \
        } else {                                                                     \
          int nv = nu - 32;                                                          \
          int il = nv >> 2, bq = nv & 3;                                             \
          int b_l = bq * 4 + (lane >> 4), ky2 = (lane & 15) * 2;                     \
          const float2* src = vc + ((size_t)b_l * CH + i0_ + il) * NMODE +           \
                              u * KY + ky2;                                          \
          async16(src, dst0 + 32768 + (size_t)nv * 1024 + lane * 16);                \
        }                                                                            \
      }                                                                              \
    }

  STAGE(0); STAGE(1);
  for (int k = 0; k < 32; ++k) {
    __builtin_amdgcn_sched_barrier(0);
    if (k < 31) asm volatile("s_waitcnt vmcnt(6)" ::: "memory");   // chunk k landed; k+1 flying
    else        asm volatile("s_waitcnt vmcnt(0)" ::: "memory");
    __builtin_amdgcn_s_barrier();           // all waves see chunk k; slot (k-1)%3 free
    __builtin_amdgcn_sched_barrier(0);
    STAGE(k + 2);                           // -> slot (k+2)%3 == (k-1)%3 (safe post-barrier)
    {
      const char* slotc = (const char*)&ring[0][0] + (size_t)(k % 3) * 49152;
      const float*  Wb = (const float*)slotc;
      const float2* Vb = (const float2*)(slotc + 32768);
      #pragma unroll
      for (int il = 0; il < 4; ++il) {
        float wrv[4], wiv[4];
        #pragma unroll
        for (int j = 0; j < 4; ++j) {
          wrv[j] = Wb[il * 1024 + (oh * 4 + j) * 32 + ky];
          wiv[j] = Wb[4096 + il * 1024 + (oh * 4 + j) * 32 + ky];
        }
        #pragma unroll
        for (int bb = 0; bb < 8; ++bb) {
          float2 v = Vb[il * 512 + (bh * 8 + bb) * 32 + ky];
          #pragma unroll
          for (int j = 0; j < 4; ++j) {
            accR[j][bb] += wrv[j] * v.x - wiv[j] * v.y;
            accI[j][bb] += wrv[j] * v.y + wiv[j] * v.x;
          }
        }
      }
    }
  }
  #undef STAGE
  #pragma unroll
  for (int j = 0; j < 4; ++j)
    #pragma unroll
    for (int bb = 0; bb < 8; ++bb) {
      int o = o0 + oh * 4 + j, b = bh * 8 + bb;
      oc[(((size_t)b * CH + o) * U + u) * KY + ky] = make_float2(accR[j][bb], accI[j][bb]);
    }
}

// ---------------- K3b: Hermitian projection of ky=0 column ----------------
__global__ __launch_bounds__(256) void k_proj0(float2* __restrict__ vc) {
  int idx = blockIdx.x * 256 + threadIdx.x;   // B*CH*33
  if (idx >= B * CH * 33) return;
  int pi = idx % 33;
  int bc = idx / 33;
  float2* base = vc + (size_t)bc * NMODE;
  if (pi == 0) {
    base[0].y = 0.f;
  } else if (pi == 32) {
    base[32 * KY].x *= 0.5f;
    base[32 * KY].y *= 0.5f;
  } else {
    int ua = pi, ub = 64 - pi;
    float2 a = base[ua * KY], b2 = base[ub * KY];
    base[ua * KY] = make_float2(0.5f * (a.x + b2.x), 0.5f * (a.y - b2.y));
    base[ub * KY] = make_float2(0.5f * (b2.x + a.x), 0.5f * (b2.y - a.y));
  }
}

// ---------------- K4: pw1 in spectral space (float2 io), XCD-pinned per batch ----------------
__global__ __launch_bounds__(256) void k_pw1(const float2* __restrict__ xc,
                                             const float* __restrict__ pw1,
                                             float2* __restrict__ hc) {
  __shared__ float wT[CH][CH + 1];
  int bid = blockIdx.x;
  int b = ((bid & 7) << 1) | ((bid >> 8) & 1);
  int jt = (bid >> 3) & 31;
  int t = threadIdx.x;
  for (int e = t; e < CH * CH; e += 256) {
    int p = e >> 7, c = e & 127;
    wT[c][p] = pw1[e];
  }
  __syncthreads();
  int tx = t & 15, ty = t >> 4;
  int j0 = jt * 64 + tx * 4;
  float accR[4][8] = {}, accI[4][8] = {};
  for (int c = 0; c < CH; ++c) {
    const float4* x4 = (const float4*)&xc[((size_t)b * CH + c) * NMODE + j0];
    float4 v0 = x4[0], v1 = x4[1];
    float xrv[4] = {v0.x, v0.z, v1.x, v1.z};
    float xiv[4] = {v0.y, v0.w, v1.y, v1.w};
    float w[8];
    #pragma unroll
    for (int pp = 0; pp < 8; ++pp) w[pp] = wT[c][ty * 8 + pp];
    #pragma unroll
    for (int jj = 0; jj < 4; ++jj)
      #pragma unroll
      for (int pp = 0; pp < 8; ++pp) {
        accR[jj][pp] += w[pp] * xrv[jj];
        accI[jj][pp] += w[pp] * xiv[jj];
      }
  }
  #pragma unroll
  for (int pp = 0; pp < 8; ++pp) {
    int p = ty * 8 + pp;
    float4* o4 = (float4*)&hc[((size_t)b * CH + p) * NMODE + j0];
    o4[0] = make_float4(accR[0][pp], accI[0][pp], accR[1][pp], accI[1][pp]);
    o4[1] = make_float4(accR[2][pp], accI[2][pp], accR[3][pp], accI[3][pp]);
  }
}

// ---------------- K5: fused iDFT + bias + gelu + pw2, parity + async dbuf + E-tile ----------------
// grid = 4096: b = (bid&7)|(((bid>>3)&1)<<3) (XCD-pinned b), pg = (bid>>4)&31, xs = bid>>9.
__global__ __launch_bounds__(256) void k_idft_partial(const float2* __restrict__ hc,
                                                      const float* __restrict__ pb1,
                                                      const float* __restrict__ pw2,
                                                      float* __restrict__ partial) {
  __shared__ float2 tw[DIM];                  // 1 KB
  __shared__ float2 hfs[2][NMODE];            // 32 KB dbuf
  __shared__ float2 sbuf[16][KY];             // [x-slot][ky] 4 KB
  __shared__ float4 sE[8][32];                // E-tile 4 KB
  int bid = blockIdx.x;
  int b = (bid & 7) | (((bid >> 3) & 1) << 3);
  int pg = (bid >> 4) & 31, xs = bid >> 9;
  int x0 = xs * 8;
  int t = threadIdx.x;
  int wv = t >> 6, lane = t & 63;
  if (t < 128) {
    float ang = (float)(2.0 * M_PI) * (float)t / 128.0f;
    tw[t] = make_float2(cosf(ang), sinf(ang));
  }

  #define STAGE_H(bf, pp_)                                                           \
    {                                                                                \
      const char* srcb = (const char*)(hc + ((size_t)b * CH + pg * PPG + (pp_)) * NMODE); \
      _Pragma("unroll")                                                              \
      for (int n = 0; n < 4; ++n) {                                                  \
        int nu = wv * 4 + n;                                                         \
        async16(srcb + (size_t)nu * 1024 + lane * 16,                                \
                (char*)&hfs[bf][0] + (size_t)nu * 1024 + lane * 16);                 \
      }                                                                              \
    }

  STAGE_H(0, 0);
  __syncthreads();                            // tw + hfs[0] ready
  {
    int xq = t >> 5, j = t & 31;
    int x = x0 + xq;
    int kxE = (j < 16) ? (2 * j) : (2 * j + 64);
    float2 wE = tw[(kxE * x) & 127];
    float2 wO = tw[((kxE + 1) * x) & 127];
    sE[xq][j] = make_float4(wE.x, wE.y, wO.x, wO.y);
  }
  int y = t & 63, xh = t >> 6;
  float Cr[KY], Sr[KY];
  #pragma unroll
  for (int ky = 0; ky < KY; ++ky) {
    float2 w = tw[(ky * y) & 127];
    float wk = (ky == 0) ? 1.f : 2.f;
    Cr[ky] = wk * w.x;
    Sr[ky] = -wk * w.y;
  }
  __syncthreads();                            // sE visible to all
  int xqA = t >> 5, kyA = t & 31;
  float res[8] = {0.f, 0.f, 0.f, 0.f, 0.f, 0.f, 0.f, 0.f};
  for (int pp = 0; pp < PPG; ++pp) {
    int p = pg * PPG + pp;
    int cur = pp & 1;
    if (pp) __syncthreads();                  // hfs[cur] staged; sbuf free
    if (pp + 1 < PPG) STAGE_H(cur ^ 1, pp + 1);
    // phase A with u-parity via E-tile: s[x]=Pe+Po, s[x+64]=Pe-Po
    {
      float per = 0.f, pei = 0.f, por = 0.f, poi = 0.f;
      #pragma unroll
      for (int j = 0; j < 32; ++j) {
        float4 E = sE[xqA][j];
        float2 h0 = hfs[cur][(2 * j) * KY + kyA];
        float2 h1 = hfs[cur][(2 * j + 1) * KY + kyA];
        per += h0.x * E.x - h0.y * E.y;
        pei += h0.x * E.y + h0.y * E.x;
        por += h1.x * E.z - h1.y * E.w;
        poi += h1.x * E.w + h1.y * E.z;
      }
      sbuf[xqA][kyA]     = make_float2(per + por, pei + poi);
      sbuf[xqA + 8][kyA] = make_float2(per - por, pei - poi);
    }
    __syncthreads();
    // phase B with ky-parity: out[y] = Ae+Ao, out[y+64] = Ae-Ao (float4 sbuf reads)
    float pb = pb1[p], pw = pw2[p];
    #pragma unroll
    for (int sl = 0; sl < 4; ++sl) {
      int s_i = xh + sl * 4;
      float ae = 0.f, ao = 0.f;
      #pragma unroll
      for (int ky = 0; ky < KY; ky += 2) {
        float4 v = *(const float4*)&sbuf[s_i][ky];   // {re_ky, im_ky, re_ky1, im_ky1}
        ae += v.x * Cr[ky] + v.y * Sr[ky];
        ao += v.z * Cr[ky + 1] + v.w * Sr[ky + 1];
      }
      float hlo = (ae + ao) * (1.f / 16384.f) + pb;
      float hhi = (ae - ao) * (1.f / 16384.f) + pb;
      float zlo = 1.5957691216057308f * (hlo + 0.044715f * hlo * hlo * hlo);
      float zhi = 1.5957691216057308f * (hhi + 0.044715f * hhi * hhi * hhi);
      res[sl * 2]     += pw * hlo * __builtin_amdgcn_rcpf(1.f + __expf(-zlo));
      res[sl * 2 + 1] += pw * hhi * __builtin_amdgcn_rcpf(1.f + __expf(-zhi));
    }
  }
  #undef STAGE_H
  size_t pbase = ((size_t)pg * B + b) * N2;
  #pragma unroll
  for (int sl = 0; sl < 4; ++sl) {
    int s_i = xh + sl * 4;
    int x = x0 + (s_i & 7) + ((s_i >> 3) << 6);
    partial[pbase + x * DIM + y]      = res[sl * 2];
    partial[pbase + x * DIM + y + 64] = res[sl * 2 + 1];
  }
}

// ---------------- K6: reduce p-group partials + pb2 ----------------
__global__ __launch_bounds__(256) void k_reduce(const float* __restrict__ partial,
                                                const float* __restrict__ pb2,
                                                float* __restrict__ outp) {
  int idx = blockIdx.x * 256 + threadIdx.x;
  if (idx >= B * N2) return;
  float s = pb2[0];
  #pragma unroll
  for (int pg = 0; pg < PG; ++pg) s += partial[(size_t)pg * B * N2 + idx];
  outp[idx] = s;
}

extern "C" void kernel_launch(void* const* d_in, const int* in_sizes, int n_in,
                              void* d_out, int out_size, void* d_ws, size_t ws_size,
                              hipStream_t stream) {
  const float* z   = (const float*)d_in[0];
  const float* lw  = (const float*)d_in[1];
  const float* lb  = (const float*)d_in[2];
  const float* wr1 = (const float*)d_in[3];
  const float* wi1 = (const float*)d_in[4];
  const float* wr2 = (const float*)d_in[5];
  const float* wi2 = (const float*)d_in[6];
  const float* pw1 = (const float*)d_in[7];
  const float* pb1 = (const float*)d_in[8];
  const float* pw2 = (const float*)d_in[9];
  const float* pb2 = (const float*)d_in[10];
  float* out = (float*)d_out;
  float* ws = (float*)d_ws;

  float* zfr = ws;
  float* zfi = zfr + 32768;
  float2* Ac = (float2*)(ws + 65536);
  float2* Bc = Ac + (size_t)B * CH * NMODE;
  float2* t1 = Bc;   // aliases Bc (dead until first k_spec write)

  k_zf1<<<B * 8, 256, 0, stream>>>(z, t1);
  k_zf2<<<B * 2, 256, 0, stream>>>(t1, zfr, zfi);
  k_lift<<<(B * CH * NMODE) / 256, 256, 0, stream>>>(zfr, zfi, lw, lb, Ac);

  const size_t WSTRIDE = (size_t)CH * CH * MODES * MODES;
  float2 *ir = Ac, *oc = Bc;
  for (int l = 0; l < NLAYERS; ++l) {
    k_spec<<<256, 512, 0, stream>>>(ir,
                                    wr1 + l * WSTRIDE, wi1 + l * WSTRIDE,
                                    wr2 + l * WSTRIDE, wi2 + l * WSTRIDE,
                                    oc);
    if (l < NLAYERS - 1)
      k_proj0<<<(B * CH * 33 + 255) / 256, 256, 0, stream>>>(oc);
    float2* tmp = ir; ir = oc; oc = tmp;
  }
  k_pw1<<<512, 256, 0, stream>>>(ir, pw1, oc);
  float* partial = (float*)ir;   // aliases Ac (33.5 MB < 67 MB, dead after k_pw1)
  k_idft_partial<<<B * PG * 8, 256, 0, stream>>>(oc, pb1, pw2, partial);
  k_reduce<<<(B * N2) / 256, 256, 0, stream>>>(partial, pb2, out);
}

// Round 16
// 766.615 us; speedup vs baseline: 1.1981x; 1.0659x over previous
//
#include <hip/hip_runtime.h>
#include <math.h>

#define B 16
#define CH 128
#define DIM 128
#define MODES 32
#define NLAYERS 4
#define PROJ 128
#define U 64            // stored kx modes: u<32 -> kx=u ; u>=32 -> kx=u+64 (96..127)
#define KY 32
#define NMODE (U*KY)    // 2048
#define N2 (DIM*DIM)    // 16384
#define PG 32           // p-groups in idft
#define PPG (PROJ/PG)   // 4 p per group

__device__ __forceinline__ void async16(const void* g, void* l) {
  __builtin_amdgcn_global_load_lds((const __attribute__((address_space(1))) unsigned int*)g,
                                   (__attribute__((address_space(3))) unsigned int*)l, 16, 0, 0);
}

// ---------------- K1a: t1[b][x][ky] = sum_y z[b][x][y] e^{-2pi i ky y/128} ----------------
__global__ __launch_bounds__(256) void k_zf1(const float* __restrict__ z,
                                             float2* __restrict__ t1) {
  __shared__ float zrow[16][DIM];
  __shared__ float2 tw[DIM];
  int bid = blockIdx.x;
  int b = bid >> 3, xt = bid & 7;
  int x0 = xt * 16;
  int t = threadIdx.x;
  if (t < 128) {
    float ang = (float)(2.0 * M_PI) * (float)t / 128.0f;
    tw[t] = make_float2(cosf(ang), sinf(ang));
  }
  for (int e = t; e < 16 * DIM / 4; e += 256)
    ((float4*)&zrow[0][0])[e] = ((const float4*)&z[b * N2 + x0 * DIM])[e];
  __syncthreads();
  #pragma unroll
  for (int j = 0; j < 2; ++j) {
    int it = t + j * 256;
    int x_l = it >> 5, ky = it & 31;
    float tr = 0.f, ti = 0.f;
    for (int y = 0; y < DIM; ++y) {
      float v = zrow[x_l][y];
      float2 w = tw[(ky * y) & 127];
      tr += v * w.x;
      ti -= v * w.y;
    }
    t1[((size_t)b * DIM + x0 + x_l) * KY + ky] = make_float2(tr, ti);
  }
}

// ---------------- K1b: zf[b][u][ky] = sum_x t1[b][x][ky] e^{-2pi i kx x/128} ----------------
__global__ __launch_bounds__(256) void k_zf2(const float2* __restrict__ t1,
                                             float* __restrict__ zfr, float* __restrict__ zfi) {
  __shared__ float2 t1s[DIM][KY];
  __shared__ float2 tw[DIM];
  int bid = blockIdx.x;
  int b = bid >> 1, uh = bid & 1;
  int t = threadIdx.x;
  if (t < 128) {
    float ang = (float)(2.0 * M_PI) * (float)t / 128.0f;
    tw[t] = make_float2(cosf(ang), sinf(ang));
  }
  for (int e = t; e < DIM * KY / 2; e += 256)
    ((float4*)&t1s[0][0])[e] = ((const float4*)&t1[(size_t)b * DIM * KY])[e];
  __syncthreads();
  #pragma unroll
  for (int j = 0; j < 4; ++j) {
    int m = t + j * 256;
    int u_l = m >> 5, ky = m & 31;
    int u = uh * 32 + u_l;
    int kx = (u < 32) ? u : (u + 64);
    float ar = 0.f, ai = 0.f;
    for (int x = 0; x < DIM; ++x) {
      float2 v = t1s[x][ky];
      float2 w = tw[(kx * x) & 127];
      ar += v.x * w.x + v.y * w.y;
      ai += v.y * w.x - v.x * w.y;
    }
    zfr[b * NMODE + u * KY + ky] = ar;
    zfi[b * NMODE + u * KY + ky] = ai;
  }
}

// ---------------- K2: lift in spectral space (float2 out) ----------------
__global__ __launch_bounds__(256) void k_lift(const float* __restrict__ zfr, const float* __restrict__ zfi,
                                              const float* __restrict__ lw, const float* __restrict__ lb,
                                              float2* __restrict__ vcout) {
  int idx = blockIdx.x * 256 + threadIdx.x;
  if (idx >= B * CH * NMODE) return;
  int m = idx & (NMODE - 1);
  int c = (idx >> 11) & 127;
  int b = idx >> 18;
  float w = lw[c];
  float re = w * zfr[b * NMODE + m];
  float im = w * zfi[b * NMODE + m];
  if (m == 0) re += 16384.f * lb[c];
  vcout[idx] = make_float2(re, im);
}

// ---------------- K3: spectral einsum, one layer ----------------
// Rate model (r8..r15): per-CU staging rate saturates at 4 blocks/CU (~22.7 GB/s/CU);
// time = staged_bytes / rate. ky-SPLIT multiplies blocks WITHOUT adding duplication:
// block = (u, o-tile 16, ky-half 16) x all 16 b -> grid 1024 (4/CU), staged bytes
// = W x1 (268 MB) + V x8 (268 MB) = 536 MB (r8's rate at r13's bytes).
// 64B-contiguous lane runs (full cache lines). LDS 16 KB dbuf (chunk = 2i = 8 KB,
// 2 async16/wave/chunk). Same-u blocks (8ot x 2kyh) pinned to one XCD.
__global__ __launch_bounds__(256) void k_spec(const float2* __restrict__ vc,
                                              const float* __restrict__ wr1, const float* __restrict__ wi1,
                                              const float* __restrict__ wr2, const float* __restrict__ wi2,
                                              float2* __restrict__ oc) {
  __shared__ float  lW[2][2][2][16][16];    // [buf][ri][il][o16][ky16] 4 KB/buf
  __shared__ float2 lV[2][2][16][16];       // [buf][il][b16][ky16]     4 KB/buf
  int bid = blockIdx.x;
  int u = ((bid & 7) << 3) | ((bid >> 3) & 7);
  int rest = bid >> 6;                      // 0..15
  int ot = rest & 7, kyh = rest >> 3;
  int o0 = ot * 16;
  int ky0 = kyh * 16;
  int kxw = u & 31;
  const float* wr = (u >= 32) ? wr2 : wr1;
  const float* wi = (u >= 32) ? wi2 : wi1;
  int t = threadIdx.x;
  int ky = t & 15, oh = (t >> 4) & 3, bq = t >> 6;   // o = o0+oh*4+j, b = bq*4+bb
  int wv = t >> 6, lane = t & 63;
  float accR[4][4] = {}, accI[4][4] = {};

  // chunk = 2 i = 8 KB: units 0..3 = W [ri][il], units 4..7 = V [il][b-half].
  // Each wave issues exactly 2 async16 per chunk. LDS dest linear (= lane*16).
  #define STAGE(bf, i0)                                                              \
    {                                                                                \
      _Pragma("unroll")                                                              \
      for (int n = 0; n < 2; ++n) {                                                  \
        int nu = wv * 2 + n;                                                         \
        if (nu < 4) {                                                                \
          int ri = nu >> 1, il = nu & 1;                                             \
          int o_l = lane >> 2, kyq = lane & 3;                                       \
          const float* src = (ri ? wi : wr) +                                        \
            (((size_t)((i0) + il) * CH + o0 + o_l) * MODES + kxw) * MODES +          \
            ky0 + kyq * 4;                                                           \
          async16(src, (char*)&lW[bf][0][0][0][0] + (size_t)nu * 1024 + lane * 16);  \
        } else {                                                                     \
          int nv = nu - 4;                                                           \
          int il = nv >> 1, bhf = nv & 1;                                            \
          int b_l = bhf * 8 + (lane >> 3), kyd = lane & 7;                           \
          const float2* src = vc + ((size_t)b_l * CH + (i0) + il) * NMODE +          \
                              u * KY + ky0 + kyd * 2;                                \
          async16(src, (char*)&lV[bf][0][0][0] + (size_t)nv * 1024 + lane * 16);     \
        }                                                                            \
      }                                                                              \
    }

  #define COMPUTE(bf)                                                                \
    {                                                                                \
      _Pragma("unroll")                                                              \
      for (int il = 0; il < 2; ++il) {                                               \
        float wrv[4], wiv[4];                                                        \
        _Pragma("unroll")                                                            \
        for (int j = 0; j < 4; ++j) {                                                \
          wrv[j] = lW[bf][0][il][oh * 4 + j][ky];                                    \
          wiv[j] = lW[bf][1][il][oh * 4 + j][ky];                                    \
        }                                                                            \
        _Pragma("unroll")                                                            \
        for (int bb = 0; bb < 4; ++bb) {                                             \
          float2 v = lV[bf][il][bq * 4 + bb][ky];                                    \
          _Pragma("unroll")                                                          \
          for (int j = 0; j < 4; ++j) {                                              \
            accR[j][bb] += wrv[j] * v.x - wiv[j] * v.y;                              \
            accI[j][bb] += wrv[j] * v.y + wiv[j] * v.x;                              \
          }                                                                          \
        }                                                                            \
      }                                                                              \
    }

  STAGE(0, 0);
  for (int k = 0; k < 64; ++k) {
    int cur = k & 1;
    __syncthreads();                        // chunk k staged; prior buf reads done
    if (k + 1 < 64) STAGE(cur ^ 1, (k + 1) * 2);
    COMPUTE(cur);
  }
  #undef STAGE
  #undef COMPUTE
  #pragma unroll
  for (int j = 0; j < 4; ++j)
    #pragma unroll
    for (int bb = 0; bb < 4; ++bb) {
      int o = o0 + oh * 4 + j, b = bq * 4 + bb;
      oc[(((size_t)b * CH + o) * U + u) * KY + ky0 + ky] = make_float2(accR[j][bb], accI[j][bb]);
    }
}

// ---------------- K3b: Hermitian projection of ky=0 column ----------------
__global__ __launch_bounds__(256) void k_proj0(float2* __restrict__ vc) {
  int idx = blockIdx.x * 256 + threadIdx.x;   // B*CH*33
  if (idx >= B * CH * 33) return;
  int pi = idx % 33;
  int bc = idx / 33;
  float2* base = vc + (size_t)bc * NMODE;
  if (pi == 0) {
    base[0].y = 0.f;
  } else if (pi == 32) {
    base[32 * KY].x *= 0.5f;
    base[32 * KY].y *= 0.5f;
  } else {
    int ua = pi, ub = 64 - pi;
    float2 a = base[ua * KY], b2 = base[ub * KY];
    base[ua * KY] = make_float2(0.5f * (a.x + b2.x), 0.5f * (a.y - b2.y));
    base[ub * KY] = make_float2(0.5f * (b2.x + a.x), 0.5f * (b2.y - a.y));
  }
}

// ---------------- K4: pw1 in spectral space (float2 io), XCD-pinned per batch ----------------
__global__ __launch_bounds__(256) void k_pw1(const float2* __restrict__ xc,
                                             const float* __restrict__ pw1,
                                             float2* __restrict__ hc) {
  __shared__ float wT[CH][CH + 1];
  int bid = blockIdx.x;
  int b = ((bid & 7) << 1) | ((bid >> 8) & 1);
  int jt = (bid >> 3) & 31;
  int t = threadIdx.x;
  for (int e = t; e < CH * CH; e += 256) {
    int p = e >> 7, c = e & 127;
    wT[c][p] = pw1[e];
  }
  __syncthreads();
  int tx = t & 15, ty = t >> 4;
  int j0 = jt * 64 + tx * 4;
  float accR[4][8] = {}, accI[4][8] = {};
  for (int c = 0; c < CH; ++c) {
    const float4* x4 = (const float4*)&xc[((size_t)b * CH + c) * NMODE + j0];
    float4 v0 = x4[0], v1 = x4[1];
    float xrv[4] = {v0.x, v0.z, v1.x, v1.z};
    float xiv[4] = {v0.y, v0.w, v1.y, v1.w};
    float w[8];
    #pragma unroll
    for (int pp = 0; pp < 8; ++pp) w[pp] = wT[c][ty * 8 + pp];
    #pragma unroll
    for (int jj = 0; jj < 4; ++jj)
      #pragma unroll
      for (int pp = 0; pp < 8; ++pp) {
        accR[jj][pp] += w[pp] * xrv[jj];
        accI[jj][pp] += w[pp] * xiv[jj];
      }
  }
  #pragma unroll
  for (int pp = 0; pp < 8; ++pp) {
    int p = ty * 8 + pp;
    float4* o4 = (float4*)&hc[((size_t)b * CH + p) * NMODE + j0];
    o4[0] = make_float4(accR[0][pp], accI[0][pp], accR[1][pp], accI[1][pp]);
    o4[1] = make_float4(accR[2][pp], accI[2][pp], accR[3][pp], accI[3][pp]);
  }
}

// ---------------- K5: fused iDFT + bias + gelu + pw2, parity + async dbuf + E-tile ----------------
// grid = 4096: b = (bid&7)|(((bid>>3)&1)<<3) (XCD-pinned b), pg = (bid>>4)&31, xs = bid>>9.
__global__ __launch_bounds__(256) void k_idft_partial(const float2* __restrict__ hc,
                                                      const float* __restrict__ pb1,
                                                      const float* __restrict__ pw2,
                                                      float* __restrict__ partial) {
  __shared__ float2 tw[DIM];                  // 1 KB
  __shared__ float2 hfs[2][NMODE];            // 32 KB dbuf
  __shared__ float2 sbuf[16][KY];             // [x-slot][ky] 4 KB
  __shared__ float4 sE[8][32];                // E-tile 4 KB
  int bid = blockIdx.x;
  int b = (bid & 7) | (((bid >> 3) & 1) << 3);
  int pg = (bid >> 4) & 31, xs = bid >> 9;
  int x0 = xs * 8;
  int t = threadIdx.x;
  int wv = t >> 6, lane = t & 63;
  if (t < 128) {
    float ang = (float)(2.0 * M_PI) * (float)t / 128.0f;
    tw[t] = make_float2(cosf(ang), sinf(ang));
  }

  #define STAGE_H(bf, pp_)                                                           \
    {                                                                                \
      const char* srcb = (const char*)(hc + ((size_t)b * CH + pg * PPG + (pp_)) * NMODE); \
      _Pragma("unroll")                                                              \
      for (int n = 0; n < 4; ++n) {                                                  \
        int nu = wv * 4 + n;                                                         \
        async16(srcb + (size_t)nu * 1024 + lane * 16,                                \
                (char*)&hfs[bf][0] + (size_t)nu * 1024 + lane * 16);                 \
      }                                                                              \
    }

  STAGE_H(0, 0);
  __syncthreads();                            // tw + hfs[0] ready
  {
    int xq = t >> 5, j = t & 31;
    int x = x0 + xq;
    int kxE = (j < 16) ? (2 * j) : (2 * j + 64);
    float2 wE = tw[(kxE * x) & 127];
    float2 wO = tw[((kxE + 1) * x) & 127];
    sE[xq][j] = make_float4(wE.x, wE.y, wO.x, wO.y);
  }
  int y = t & 63, xh = t >> 6;
  float Cr[KY], Sr[KY];
  #pragma unroll
  for (int ky = 0; ky < KY; ++ky) {
    float2 w = tw[(ky * y) & 127];
    float wk = (ky == 0) ? 1.f : 2.f;
    Cr[ky] = wk * w.x;
    Sr[ky] = -wk * w.y;
  }
  __syncthreads();                            // sE visible to all
  int xqA = t >> 5, kyA = t & 31;
  float res[8] = {0.f, 0.f, 0.f, 0.f, 0.f, 0.f, 0.f, 0.f};
  for (int pp = 0; pp < PPG; ++pp) {
    int p = pg * PPG + pp;
    int cur = pp & 1;
    if (pp) __syncthreads();                  // hfs[cur] staged; sbuf free
    if (pp + 1 < PPG) STAGE_H(cur ^ 1, pp + 1);
    // phase A with u-parity via E-tile: s[x]=Pe+Po, s[x+64]=Pe-Po
    {
      float per = 0.f, pei = 0.f, por = 0.f, poi = 0.f;
      #pragma unroll
      for (int j = 0; j < 32; ++j) {
        float4 E = sE[xqA][j];
        float2 h0 = hfs[cur][(2 * j) * KY + kyA];
        float2 h1 = hfs[cur][(2 * j + 1) * KY + kyA];
        per += h0.x * E.x - h0.y * E.y;
        pei += h0.x * E.y + h0.y * E.x;
        por += h1.x * E.z - h1.y * E.w;
        poi += h1.x * E.w + h1.y * E.z;
      }
      sbuf[xqA][kyA]     = make_float2(per + por, pei + poi);
      sbuf[xqA + 8][kyA] = make_float2(per - por, pei - poi);
    }
    __syncthreads();
    // phase B with ky-parity: out[y] = Ae+Ao, out[y+64] = Ae-Ao (float4 sbuf reads)
    float pb = pb1[p], pw = pw2[p];
    #pragma unroll
    for (int sl = 0; sl < 4; ++sl) {
      int s_i = xh + sl * 4;
      float ae = 0.f, ao = 0.f;
      #pragma unroll
      for (int ky = 0; ky < KY; ky += 2) {
        float4 v = *(const float4*)&sbuf[s_i][ky];   // {re_ky, im_ky, re_ky1, im_ky1}
        ae += v.x * Cr[ky] + v.y * Sr[ky];
        ao += v.z * Cr[ky + 1] + v.w * Sr[ky + 1];
      }
      float hlo = (ae + ao) * (1.f / 16384.f) + pb;
      float hhi = (ae - ao) * (1.f / 16384.f) + pb;
      float zlo = 1.5957691216057308f * (hlo + 0.044715f * hlo * hlo * hlo);
      float zhi = 1.5957691216057308f * (hhi + 0.044715f * hhi * hhi * hhi);
      res[sl * 2]     += pw * hlo * __builtin_amdgcn_rcpf(1.f + __expf(-zlo));
      res[sl * 2 + 1] += pw * hhi * __builtin_amdgcn_rcpf(1.f + __expf(-zhi));
    }
  }
  #undef STAGE_H
  size_t pbase = ((size_t)pg * B + b) * N2;
  #pragma unroll
  for (int sl = 0; sl < 4; ++sl) {
    int s_i = xh + sl * 4;
    int x = x0 + (s_i & 7) + ((s_i >> 3) << 6);
    partial[pbase + x * DIM + y]      = res[sl * 2];
    partial[pbase + x * DIM + y + 64] = res[sl * 2 + 1];
  }
}

// ---------------- K6: reduce p-group partials + pb2 ----------------
__global__ __launch_bounds__(256) void k_reduce(const float* __restrict__ partial,
                                                const float* __restrict__ pb2,
                                                float* __restrict__ outp) {
  int idx = blockIdx.x * 256 + threadIdx.x;
  if (idx >= B * N2) return;
  float s = pb2[0];
  #pragma unroll
  for (int pg = 0; pg < PG; ++pg) s += partial[(size_t)pg * B * N2 + idx];
  outp[idx] = s;
}

extern "C" void kernel_launch(void* const* d_in, const int* in_sizes, int n_in,
                              void* d_out, int out_size, void* d_ws, size_t ws_size,
                              hipStream_t stream) {
  const float* z   = (const float*)d_in[0];
  const float* lw  = (const float*)d_in[1];
  const float* lb  = (const float*)d_in[2];
  const float* wr1 = (const float*)d_in[3];
  const float* wi1 = (const float*)d_in[4];
  const float* wr2 = (const float*)d_in[5];
  const float* wi2 = (const float*)d_in[6];
  const float* pw1 = (const float*)d_in[7];
  const float* pb1 = (const float*)d_in[8];
  const float* pw2 = (const float*)d_in[9];
  const float* pb2 = (const float*)d_in[10];
  float* out = (float*)d_out;
  float* ws = (float*)d_ws;

  float* zfr = ws;
  float* zfi = zfr + 32768;
  float2* Ac = (float2*)(ws + 65536);
  float2* Bc = Ac + (size_t)B * CH * NMODE;
  float2* t1 = Bc;   // aliases Bc (dead until first k_spec write)

  k_zf1<<<B * 8, 256, 0, stream>>>(z, t1);
  k_zf2<<<B * 2, 256, 0, stream>>>(t1, zfr, zfi);
  k_lift<<<(B * CH * NMODE) / 256, 256, 0, stream>>>(zfr, zfi, lw, lb, Ac);

  const size_t WSTRIDE = (size_t)CH * CH * MODES * MODES;
  float2 *ir = Ac, *oc = Bc;
  for (int l = 0; l < NLAYERS; ++l) {
    k_spec<<<1024, 256, 0, stream>>>(ir,
                                     wr1 + l * WSTRIDE, wi1 + l * WSTRIDE,
                                     wr2 + l * WSTRIDE, wi2 + l * WSTRIDE,
                                     oc);
    if (l < NLAYERS - 1)
      k_proj0<<<(B * CH * 33 + 255) / 256, 256, 0, stream>>>(oc);
    float2* tmp = ir; ir = oc; oc = tmp;
  }
  k_pw1<<<512, 256, 0, stream>>>(ir, pw1, oc);
  float* partial = (float*)ir;   // aliases Ac (33.5 MB < 67 MB, dead after k_pw1)
  k_idft_partial<<<B * PG * 8, 256, 0, stream>>>(oc, pb1, pw2, partial);
  k_reduce<<<(B * N2) / 256, 256, 0, stream>>>(partial, pb2, out);
}